// Round 1
// baseline (206.811 us; speedup 1.0000x reference)
//
#include <hip/hip_runtime.h>
#include <stdint.h>

// ---------------------------------------------------------------------------
// MultiHeadPointAttention (B=2, N=8192, K=16, H=4, Cin=64, Cout=128, D=32)
//
// Pipeline:
//   prep_frags : weights -> bf16 MFMA B-fragment layout in ws (Wqkv/Wo split hi/lo)
//   qkv_kernel : q,k,v = x @ [Wq|Wkv] + bias            (split-bf16 MFMA, ~f32 acc)
//   fused_attn : per node (one wave): pos MLP, rel MLP, softmax, aggregation
//   wo_kernel  : out = agg @ Wo + bo                    (split-bf16 MFMA)
//
// MFMA 16x16x32 bf16 layouts (HW-verified per guide):
//   A[m][k]: m = lane&15, k = (lane>>4)*8 + j   (j = elem 0..7)
//   B[k][n]: n = lane&15, k = (lane>>4)*8 + j
//   D[r][c]: c = lane&15, r = (lane>>4)*4 + reg
// ---------------------------------------------------------------------------

typedef __attribute__((ext_vector_type(8))) short short8;
typedef __attribute__((ext_vector_type(4))) float f32x4;

#define NN_TOT 16384   // B*N
#define PES 136        // LDS row stride in bf16 elems (16B-aligned, conflict-breaking)

__device__ __forceinline__ short f2bf_rne(float f) {
  uint32_t u = __builtin_bit_cast(uint32_t, f);
  uint32_t r = (u + 0x7FFFu + ((u >> 16) & 1u)) >> 16;
  return (short)r;
}
__device__ __forceinline__ float bf2f(unsigned short s) {
  uint32_t u = ((uint32_t)s) << 16;
  return __builtin_bit_cast(float, u);
}

// ---------------------------------------------------------------------------
// ws layout (bytes):
//   0       fqh  (qkv hi frags)  24t*2s*64*8*2 = 49152
//   49152   fql  (qkv lo frags)                 49152
//   98304   fwp2                 8t*4s*64*8*2 = 32768
//   131072  fwa1                                32768
//   163840  fwa2                                32768
//   196608  fwoh                                32768
//   229376  fwol                                32768
//   262144  q  f32[16384*128]   8 MB
//   +8MB    k, +16MB v, +24MB agg   (total ~33.8 MB)
// ---------------------------------------------------------------------------

__global__ __launch_bounds__(256) void prep_frags(
    const float* __restrict__ Wq, const float* __restrict__ Wkv,
    const float* __restrict__ Wp2, const float* __restrict__ Wa1,
    const float* __restrict__ Wa2, const float* __restrict__ Wo,
    short* __restrict__ fqh, short* __restrict__ fql,
    short* __restrict__ fwp2, short* __restrict__ fwa1, short* __restrict__ fwa2,
    short* __restrict__ fwoh, short* __restrict__ fwol) {
  int r = blockIdx.x * 256 + threadIdx.x;   // lane-row id, grid = 44*256 = 11264 exact
  if (r < 3072) {
    // qkv frags: r = (t*2+s)*64 + lane, t<24, K=64 (s<2), N-col = 16t+l15
    int t = r >> 7, rem = r & 127, s = rem >> 6, lane = rem & 63;
    int quad = lane >> 4, l15 = lane & 15;
    int col = t * 16 + l15;
    #pragma unroll
    for (int j = 0; j < 8; j++) {
      int i = 32 * s + quad * 8 + j;
      float wv = (col < 128) ? Wq[i * 128 + col] : Wkv[i * 256 + (col - 128)];
      short hi = f2bf_rne(wv);
      fqh[r * 8 + j] = hi;
      fql[r * 8 + j] = f2bf_rne(wv - bf2f((unsigned short)hi));
    }
  } else {
    // 128x128 mats: rr = (t*4+s)*64 + lane, t<8, s<4
    int r2 = r - 3072;
    int mat = r2 >> 11;        // 0:Wp2 1:Wa1 2:Wa2 3:Wo
    int rr = r2 & 2047;
    int t = rr >> 8, rem = rr & 255, s = rem >> 6, lane = rem & 63;
    int quad = lane >> 4, l15 = lane & 15;
    int col = t * 16 + l15;
    const float* W = (mat == 0) ? Wp2 : (mat == 1) ? Wa1 : (mat == 2) ? Wa2 : Wo;
    #pragma unroll
    for (int j = 0; j < 8; j++) {
      int i = 32 * s + quad * 8 + j;
      float wv = W[i * 128 + col];
      short hi = f2bf_rne(wv);
      if (mat == 3) {
        fwoh[rr * 8 + j] = hi;
        fwol[rr * 8 + j] = f2bf_rne(wv - bf2f((unsigned short)hi));
      } else if (mat == 0) fwp2[rr * 8 + j] = hi;
      else if (mat == 1)   fwa1[rr * 8 + j] = hi;
      else                 fwa2[rr * 8 + j] = hi;
    }
  }
}

// q,k,v projection: one wave handles 16 nodes x 384 cols; K=64 (2 k-steps).
// Split bf16 (hi/lo) on both operands -> near-f32 accuracy.
__global__ __launch_bounds__(256) void qkv_kernel(
    const float* __restrict__ x, const float* __restrict__ bq,
    const float* __restrict__ bkv,
    const short* __restrict__ fqh, const short* __restrict__ fql,
    float* __restrict__ q, float* __restrict__ k, float* __restrict__ v) {
  int wid = blockIdx.x * 4 + (threadIdx.x >> 6);
  int lane = threadIdx.x & 63, quad = lane >> 4, l15 = lane & 15;
  int base = wid * 16;

  short8 ah[2], al[2];
  #pragma unroll
  for (int s = 0; s < 2; s++) {
    const float* xp = x + (base + l15) * 64 + 32 * s + quad * 8;
    f32x4 x0 = *reinterpret_cast<const f32x4*>(xp);
    f32x4 x1 = *reinterpret_cast<const f32x4*>(xp + 4);
    #pragma unroll
    for (int j = 0; j < 4; j++) {
      short h0 = f2bf_rne(x0[j]);
      ah[s][j] = h0; al[s][j] = f2bf_rne(x0[j] - bf2f((unsigned short)h0));
      short h1 = f2bf_rne(x1[j]);
      ah[s][j + 4] = h1; al[s][j + 4] = f2bf_rne(x1[j] - bf2f((unsigned short)h1));
    }
  }

  #pragma unroll
  for (int t = 0; t < 24; t++) {
    f32x4 acc = {0.f, 0.f, 0.f, 0.f};
    #pragma unroll
    for (int s = 0; s < 2; s++) {
      short8 bh = *reinterpret_cast<const short8*>(fqh + ((t * 2 + s) * 64 + lane) * 8);
      short8 bl = *reinterpret_cast<const short8*>(fql + ((t * 2 + s) * 64 + lane) * 8);
      acc = __builtin_amdgcn_mfma_f32_16x16x32_bf16(ah[s], bh, acc, 0, 0, 0);
      acc = __builtin_amdgcn_mfma_f32_16x16x32_bf16(ah[s], bl, acc, 0, 0, 0);
      acc = __builtin_amdgcn_mfma_f32_16x16x32_bf16(al[s], bh, acc, 0, 0, 0);
    }
    int c = t * 16 + l15;
    float bias;
    float* dst;
    if (c < 128)      { bias = bq[c];        dst = q + c; }
    else if (c < 256) { bias = bkv[c - 128]; dst = k + (c - 128); }
    else              { bias = bkv[c - 128]; dst = v + (c - 256); }
    #pragma unroll
    for (int r = 0; r < 4; r++) {
      int node = base + quad * 4 + r;
      dst[node * 128] = acc[r] + bias;
    }
  }
}

// Fused per-node attention: one wave per node (M = 16 neighbors).
__global__ __launch_bounds__(256) void fused_attn(
    const float* __restrict__ pos, const int* __restrict__ idx,
    const float* __restrict__ Wp1, const float* __restrict__ bp1,
    const float* __restrict__ bp2, const float* __restrict__ ba1,
    const float* __restrict__ ba2,
    const short* __restrict__ fwp2, const short* __restrict__ fwa1,
    const short* __restrict__ fwa2,
    const float* __restrict__ qg, const float* __restrict__ kg,
    const float* __restrict__ vg, float* __restrict__ agg) {
  __shared__ __align__(16) unsigned short pe_s[4][16 * PES];   // pos_enc bf16
  __shared__ __align__(16) unsigned short hid_s[4][16 * PES];  // hidden bf16 (reused)
  __shared__ int sidx[4][16];
  __shared__ float spd[4][16][4];
  __shared__ __align__(16) float sq[4][128];

  const int w = threadIdx.x >> 6;
  const int lane = threadIdx.x & 63;
  const int quad = lane >> 4;
  const int l15 = lane & 15;
  const int nn = blockIdx.x * 4 + w;        // flat node id, < 16384
  const int b = nn >> 13;

  // ---- stage neighbor idx, pos_diff, q ----
  if (lane < 16) {
    int ji = idx[nn * 16 + lane];
    int jn = b * 8192 + ji;
    sidx[w][lane] = jn;
    spd[w][lane][0] = pos[nn * 3 + 0] - pos[jn * 3 + 0];
    spd[w][lane][1] = pos[nn * 3 + 1] - pos[jn * 3 + 1];
    spd[w][lane][2] = pos[nn * 3 + 2] - pos[jn * 3 + 2];
  }
  sq[w][lane]      = qg[nn * 128 + lane];
  sq[w][lane + 64] = qg[nn * 128 + 64 + lane];
  __syncthreads();

  // ---- pos MLP layer 1 (f32 VALU): relu(pos_diff @ Wp1 + bp1) -> hid_s ----
  {
    const int c0 = lane, c1 = lane + 64;
    float w00 = Wp1[c0], w01 = Wp1[128 + c0], w02 = Wp1[256 + c0], b0 = bp1[c0];
    float w10 = Wp1[c1], w11 = Wp1[128 + c1], w12 = Wp1[256 + c1], b1 = bp1[c1];
    #pragma unroll
    for (int m = 0; m < 16; m++) {
      float d0 = spd[w][m][0], d1 = spd[w][m][1], d2 = spd[w][m][2];
      float h0 = fmaxf(b0 + d0 * w00 + d1 * w01 + d2 * w02, 0.f);
      float h1 = fmaxf(b1 + d0 * w10 + d1 * w11 + d2 * w12, 0.f);
      hid_s[w][m * PES + c0] = (unsigned short)f2bf_rne(h0);
      hid_s[w][m * PES + c1] = (unsigned short)f2bf_rne(h1);
    }
  }
  __syncthreads();

  f32x4 acc[8];

  // ---- GEMM1: pos_enc = pos_hidden @ Wp2 + bp2 -> pe_s (bf16) ----
  #pragma unroll
  for (int t = 0; t < 8; t++) acc[t] = (f32x4){0.f, 0.f, 0.f, 0.f};
  #pragma unroll
  for (int s = 0; s < 4; s++) {
    short8 a = *reinterpret_cast<const short8*>(&hid_s[w][l15 * PES + 32 * s + quad * 8]);
    #pragma unroll
    for (int t = 0; t < 8; t++) {
      short8 bf = *reinterpret_cast<const short8*>(fwp2 + ((t * 4 + s) * 64 + lane) * 8);
      acc[t] = __builtin_amdgcn_mfma_f32_16x16x32_bf16(a, bf, acc[t], 0, 0, 0);
    }
  }
  #pragma unroll
  for (int t = 0; t < 8; t++) {
    int c = 16 * t + l15;
    float bb = bp2[c];
    #pragma unroll
    for (int r = 0; r < 4; r++)
      pe_s[w][(quad * 4 + r) * PES + c] = (unsigned short)f2bf_rne(acc[t][r] + bb);
  }
  __syncthreads();

  // ---- GEMM2: rel = (k_n - q + pos_enc);  hidden = relu(rel @ Wa1 + ba1) ----
  #pragma unroll
  for (int t = 0; t < 8; t++) acc[t] = (f32x4){0.f, 0.f, 0.f, 0.f};
  {
    const float* kp = kg + sidx[w][l15] * 128;
    #pragma unroll
    for (int s = 0; s < 4; s++) {
      int ch0 = 32 * s + quad * 8;
      f32x4 k0 = *reinterpret_cast<const f32x4*>(kp + ch0);
      f32x4 k1 = *reinterpret_cast<const f32x4*>(kp + ch0 + 4);
      f32x4 q0 = *reinterpret_cast<const f32x4*>(&sq[w][ch0]);
      f32x4 q1 = *reinterpret_cast<const f32x4*>(&sq[w][ch0 + 4]);
      short8 pp = *reinterpret_cast<const short8*>(&pe_s[w][l15 * PES + ch0]);
      short8 a;
      #pragma unroll
      for (int j = 0; j < 4; j++) {
        a[j]     = f2bf_rne(k0[j] - q0[j] + bf2f((unsigned short)pp[j]));
        a[j + 4] = f2bf_rne(k1[j] - q1[j] + bf2f((unsigned short)pp[j + 4]));
      }
      #pragma unroll
      for (int t = 0; t < 8; t++) {
        short8 bf = *reinterpret_cast<const short8*>(fwa1 + ((t * 4 + s) * 64 + lane) * 8);
        acc[t] = __builtin_amdgcn_mfma_f32_16x16x32_bf16(a, bf, acc[t], 0, 0, 0);
      }
    }
  }
  #pragma unroll
  for (int t = 0; t < 8; t++) {
    int c = 16 * t + l15;
    float bb = ba1[c];
    #pragma unroll
    for (int r = 0; r < 4; r++)
      hid_s[w][(quad * 4 + r) * PES + c] =
          (unsigned short)f2bf_rne(fmaxf(acc[t][r] + bb, 0.f));
  }
  __syncthreads();

  // ---- GEMM3: attn = hidden @ Wa2 + ba2 ----
  #pragma unroll
  for (int t = 0; t < 8; t++) acc[t] = (f32x4){0.f, 0.f, 0.f, 0.f};
  #pragma unroll
  for (int s = 0; s < 4; s++) {
    short8 a = *reinterpret_cast<const short8*>(&hid_s[w][l15 * PES + 32 * s + quad * 8]);
    #pragma unroll
    for (int t = 0; t < 8; t++) {
      short8 bf = *reinterpret_cast<const short8*>(fwa2 + ((t * 4 + s) * 64 + lane) * 8);
      acc[t] = __builtin_amdgcn_mfma_f32_16x16x32_bf16(a, bf, acc[t], 0, 0, 0);
    }
  }

  // ---- softmax over K=16 (per channel) + aggregation ----
  int vb0 = sidx[w][quad * 4 + 0] * 128;
  int vb1 = sidx[w][quad * 4 + 1] * 128;
  int vb2 = sidx[w][quad * 4 + 2] * 128;
  int vb3 = sidx[w][quad * 4 + 3] * 128;
  #pragma unroll
  for (int t = 0; t < 8; t++) {
    int c = 16 * t + l15;
    float bb = ba2[c];
    float lg0 = acc[t][0] + bb, lg1 = acc[t][1] + bb;
    float lg2 = acc[t][2] + bb, lg3 = acc[t][3] + bb;
    float mx = fmaxf(fmaxf(lg0, lg1), fmaxf(lg2, lg3));
    mx = fmaxf(mx, __shfl_xor(mx, 16));
    mx = fmaxf(mx, __shfl_xor(mx, 32));
    float e0 = __expf(lg0 - mx), e1 = __expf(lg1 - mx);
    float e2 = __expf(lg2 - mx), e3 = __expf(lg3 - mx);
    float ls = e0 + e1 + e2 + e3;
    ls += __shfl_xor(ls, 16);
    ls += __shfl_xor(ls, 32);
    float p = e0 * (vg[vb0 + c] + bf2f(pe_s[w][(quad * 4 + 0) * PES + c]))
            + e1 * (vg[vb1 + c] + bf2f(pe_s[w][(quad * 4 + 1) * PES + c]))
            + e2 * (vg[vb2 + c] + bf2f(pe_s[w][(quad * 4 + 2) * PES + c]))
            + e3 * (vg[vb3 + c] + bf2f(pe_s[w][(quad * 4 + 3) * PES + c]));
    p += __shfl_xor(p, 16);
    p += __shfl_xor(p, 32);
    if (quad == 0) agg[nn * 128 + c] = p / ls;
  }
}

// Final projection: out = agg @ Wo + bo (split bf16, one wave per 16 nodes)
__global__ __launch_bounds__(256) void wo_kernel(
    const float* __restrict__ agg, const float* __restrict__ bo,
    const short* __restrict__ fh, const short* __restrict__ fl,
    float* __restrict__ out) {
  int wid = blockIdx.x * 4 + (threadIdx.x >> 6);
  int lane = threadIdx.x & 63, quad = lane >> 4, l15 = lane & 15;
  int base = wid * 16;

  short8 ah[4], al[4];
  #pragma unroll
  for (int s = 0; s < 4; s++) {
    const float* ap = agg + (base + l15) * 128 + 32 * s + quad * 8;
    f32x4 a0 = *reinterpret_cast<const f32x4*>(ap);
    f32x4 a1 = *reinterpret_cast<const f32x4*>(ap + 4);
    #pragma unroll
    for (int j = 0; j < 4; j++) {
      short h0 = f2bf_rne(a0[j]);
      ah[s][j] = h0; al[s][j] = f2bf_rne(a0[j] - bf2f((unsigned short)h0));
      short h1 = f2bf_rne(a1[j]);
      ah[s][j + 4] = h1; al[s][j + 4] = f2bf_rne(a1[j] - bf2f((unsigned short)h1));
    }
  }
  #pragma unroll
  for (int t = 0; t < 8; t++) {
    f32x4 acc = {0.f, 0.f, 0.f, 0.f};
    #pragma unroll
    for (int s = 0; s < 4; s++) {
      short8 bh = *reinterpret_cast<const short8*>(fh + ((t * 4 + s) * 64 + lane) * 8);
      short8 bl = *reinterpret_cast<const short8*>(fl + ((t * 4 + s) * 64 + lane) * 8);
      acc = __builtin_amdgcn_mfma_f32_16x16x32_bf16(ah[s], bh, acc, 0, 0, 0);
      acc = __builtin_amdgcn_mfma_f32_16x16x32_bf16(ah[s], bl, acc, 0, 0, 0);
      acc = __builtin_amdgcn_mfma_f32_16x16x32_bf16(al[s], bh, acc, 0, 0, 0);
    }
    int c = 16 * t + l15;
    float bb = bo[c];
    #pragma unroll
    for (int r = 0; r < 4; r++)
      out[(base + quad * 4 + r) * 128 + c] = acc[r] + bb;
  }
}

extern "C" void kernel_launch(void* const* d_in, const int* in_sizes, int n_in,
                              void* d_out, int out_size, void* d_ws, size_t ws_size,
                              hipStream_t stream) {
  const float* x   = (const float*)d_in[0];
  const float* pos = (const float*)d_in[1];
  const int*   idx = (const int*)d_in[2];
  const float* Wq  = (const float*)d_in[3];
  const float* bq  = (const float*)d_in[4];
  const float* Wkv = (const float*)d_in[5];
  const float* bkv = (const float*)d_in[6];
  const float* Wp1 = (const float*)d_in[7];
  const float* bp1 = (const float*)d_in[8];
  const float* Wp2 = (const float*)d_in[9];
  const float* bp2 = (const float*)d_in[10];
  const float* Wa1 = (const float*)d_in[11];
  const float* ba1 = (const float*)d_in[12];
  const float* Wa2 = (const float*)d_in[13];
  const float* ba2 = (const float*)d_in[14];
  const float* Wo  = (const float*)d_in[15];
  const float* bo  = (const float*)d_in[16];

  char* ws = (char*)d_ws;
  short* fqh  = (short*)(ws + 0);
  short* fql  = (short*)(ws + 49152);
  short* fwp2 = (short*)(ws + 98304);
  short* fwa1 = (short*)(ws + 131072);
  short* fwa2 = (short*)(ws + 163840);
  short* fwoh = (short*)(ws + 196608);
  short* fwol = (short*)(ws + 229376);
  float* qb = (float*)(ws + 262144);
  float* kb = qb + NN_TOT * 128;
  float* vb = kb + NN_TOT * 128;
  float* ab = vb + NN_TOT * 128;

  prep_frags<<<44, 256, 0, stream>>>(Wq, Wkv, Wp2, Wa1, Wa2, Wo,
                                     fqh, fql, fwp2, fwa1, fwa2, fwoh, fwol);
  qkv_kernel<<<256, 256, 0, stream>>>(x, bq, bkv, fqh, fql, qb, kb, vb);
  fused_attn<<<4096, 256, 0, stream>>>(pos, idx, Wp1, bp1, bp2, ba1, ba2,
                                       fwp2, fwa1, fwa2, qb, kb, vb, ab);
  wo_kernel<<<256, 256, 0, stream>>>(ab, bo, fwoh, fwol, (float*)d_out);
}